// Round 9
// baseline (236.018 us; speedup 1.0000x reference)
//
#include <hip/hip_runtime.h>
#include <math.h>

// Round 9:
//   flash: REVERT to R7 64-row tile (36.9 KB LDS, 4 blocks/CU) + VALU diet:
//          G stored f32 pre-scaled by 0.125*log2(e); softmax in exp2 domain
//          (__builtin_amdgcn_exp2f) -> kills ~49 VALU ops/lane/iter.
//   prep : pointer-array dynamic indexing -> uniform if/else chains
//          (avoids potential scratch lowering).
//   qkv  : if/else operand select; Vt epilogue via LDS transpose
//          ([col][130] padded, conflict-free) -> coalesced 16B stores.
//   wo   : unchanged.

#define BS 8
#define SEQ 1024
#define DM 512
#define NH 8
#define DK 64
#define ROWS (BS * SEQ)

typedef __bf16 bf16_t;
typedef bf16_t bf16x8 __attribute__((ext_vector_type(8)));
typedef bf16_t bf16x4 __attribute__((ext_vector_type(4)));
typedef float f32x4 __attribute__((ext_vector_type(4)));

#define GSCALE 0.18033688011112043f  // 0.125 * log2(e)

__device__ inline f32x4 mfma32(bf16x8 a, bf16x8 b, f32x4 c) {
  return __builtin_amdgcn_mfma_f32_16x16x32_bf16(a, b, c, 0, 0, 0);
}

__device__ inline void gload_lds16(const bf16_t* g, bf16_t* l) {
  __builtin_amdgcn_global_load_lds(
      (const __attribute__((address_space(1))) void*)g,
      (__attribute__((address_space(3))) void*)l, 16, 0, 0);
}

// ---------------------------------------------------------------------------
// prep: blocks [0,1664) cvt fp32->bf16; [1664,3712) wc-softmax wave-per-row,
// G = (1 + softmax(wc)) * 0.125 * log2(e), f32.
// ---------------------------------------------------------------------------
__global__ __launch_bounds__(256) void prep_kernel(
    const float* q, const float* k, const float* v,
    const float* wq, const float* wk, const float* wv, const float* wo,
    const float* wc,
    bf16_t* xq, bf16_t* xk, bf16_t* xv,
    bf16_t* wqb, bf16_t* wkb, bf16_t* wvb, bf16_t* wob,
    float* G) {
  int blk = blockIdx.x;
  int t = threadIdx.x;
  if (blk < 1664) {
    const float* src;
    bf16_t* dst;
    if (blk < 512)       { src = q  + (size_t)blk * 8192;          dst = xq  + (size_t)blk * 8192; }
    else if (blk < 1024) { src = k  + (size_t)(blk - 512) * 8192;  dst = xk  + (size_t)(blk - 512) * 8192; }
    else if (blk < 1536) { src = v  + (size_t)(blk - 1024) * 8192; dst = xv  + (size_t)(blk - 1024) * 8192; }
    else if (blk < 1568) { src = wq + (size_t)(blk - 1536) * 8192; dst = wqb + (size_t)(blk - 1536) * 8192; }
    else if (blk < 1600) { src = wk + (size_t)(blk - 1568) * 8192; dst = wkb + (size_t)(blk - 1568) * 8192; }
    else if (blk < 1632) { src = wv + (size_t)(blk - 1600) * 8192; dst = wvb + (size_t)(blk - 1600) * 8192; }
    else                 { src = wo + (size_t)(blk - 1632) * 8192; dst = wob + (size_t)(blk - 1632) * 8192; }
#pragma unroll
    for (int f = 0; f < 8; ++f) {
      int idx = (f * 256 + t) * 4;
      float4 x = *(const float4*)(src + idx);
      bf16x4 o;
      o[0] = (bf16_t)x.x; o[1] = (bf16_t)x.y; o[2] = (bf16_t)x.z; o[3] = (bf16_t)x.w;
      *(bf16x4*)(dst + idx) = o;
    }
  } else {
    int row = (blk - 1664) * 4 + (t >> 6);
    int l = t & 63;
    const float* x = wc + (size_t)row * SEQ;
    float* y = G + (size_t)row * SEQ;
    float4 vv[4];
#pragma unroll
    for (int j = 0; j < 4; ++j) vv[j] = *(const float4*)(x + l * 4 + j * 256);
    float m = -INFINITY;
#pragma unroll
    for (int j = 0; j < 4; ++j)
      m = fmaxf(m, fmaxf(fmaxf(vv[j].x, vv[j].y), fmaxf(vv[j].z, vv[j].w)));
#pragma unroll
    for (int off = 1; off < 64; off <<= 1) m = fmaxf(m, __shfl_xor(m, off, 64));
    float4 e[4];
    float s = 0.f;
#pragma unroll
    for (int j = 0; j < 4; ++j) {
      e[j].x = __expf(vv[j].x - m); e[j].y = __expf(vv[j].y - m);
      e[j].z = __expf(vv[j].z - m); e[j].w = __expf(vv[j].w - m);
      s += e[j].x + e[j].y + e[j].z + e[j].w;
    }
#pragma unroll
    for (int off = 1; off < 64; off <<= 1) s += __shfl_xor(s, off, 64);
    float inv = 1.0f / s;
#pragma unroll
    for (int j = 0; j < 4; ++j) {
      float4 g;
      g.x = (1.0f + e[j].x * inv) * GSCALE;
      g.y = (1.0f + e[j].y * inv) * GSCALE;
      g.z = (1.0f + e[j].z * inv) * GSCALE;
      g.w = (1.0f + e[j].w * inv) * GSCALE;
      *(float4*)(y + l * 4 + j * 256) = g;
    }
  }
}

// ---------------------------------------------------------------------------
// Core bf16 GEMM (pipelined, one barrier/iter): C = X @ W^T + bias.
// BN=128, BK=32.  vt_out: epilogue LDS-transpose, write Vt[bh][d][m].
// ---------------------------------------------------------------------------
template <int BM, bool OUTF32>
__device__ inline void gemm_core(const bf16_t* X, const bf16_t* W,
                                 const float* bias, void* Cv,
                                 int mblk, int nblk, bool vt_out) {
  // flat smem: As[2][BM*32] | Bs[2][128*32]; epilogue Cs[128][130] aliases all
  constexpr int SMEM_ELTS = (BM == 128) ? 16640 : (2 * BM * 32 + 2 * 128 * 32);
  __shared__ bf16_t smem[SMEM_ELTS];
  bf16_t* As = smem;
  bf16_t* Bs = smem + 2 * BM * 32;
  int t = threadIdx.x, lane = t & 63, w = t >> 6;
  int quad = lane >> 4, l15 = lane & 15;
  constexpr int MT = BM / 32;
  int m0w = (w & 1) * (BM / 2), n0w = (w >> 1) * 64;
  int mbase = mblk * BM, nbase = nblk * 128;
  int lr = lane >> 2, l4 = lane & 3;
  f32x4 acc[MT][4] = {};

#pragma unroll
  for (int f = 0; f < BM / 64; ++f) {
    int i = f * 4 + w;
    gload_lds16(X + (size_t)(mbase + i * 16 + lr) * DM + l4 * 8, &As[i * 512]);
  }
#pragma unroll
  for (int f = 0; f < 2; ++f) {
    int i = f * 4 + w;
    gload_lds16(W + (size_t)(nbase + i * 16 + lr) * DM + l4 * 8, &Bs[i * 512]);
  }

  for (int it = 0; it < 16; ++it) {
    __syncthreads();
    int cb = it & 1;
    if (it + 1 < 16) {
      int kb = (it + 1) * 32, nb = (it + 1) & 1;
#pragma unroll
      for (int f = 0; f < BM / 64; ++f) {
        int i = f * 4 + w;
        gload_lds16(X + (size_t)(mbase + i * 16 + lr) * DM + kb + l4 * 8,
                    &As[nb * BM * 32 + i * 512]);
      }
#pragma unroll
      for (int f = 0; f < 2; ++f) {
        int i = f * 4 + w;
        gload_lds16(W + (size_t)(nbase + i * 16 + lr) * DM + kb + l4 * 8,
                    &Bs[nb * 128 * 32 + i * 512]);
      }
    }
    bf16x8 af[MT], bfr[4];
#pragma unroll
    for (int mt = 0; mt < MT; ++mt)
      af[mt] = *(const bf16x8*)&As[cb * BM * 32 + (m0w + mt * 16 + l15) * 32 + quad * 8];
#pragma unroll
    for (int nt = 0; nt < 4; ++nt)
      bfr[nt] = *(const bf16x8*)&Bs[cb * 128 * 32 + (n0w + nt * 16 + l15) * 32 + quad * 8];
#pragma unroll
    for (int mt = 0; mt < MT; ++mt)
#pragma unroll
      for (int nt = 0; nt < 4; ++nt)
        acc[mt][nt] = mfma32(af[mt], bfr[nt], acc[mt][nt]);
  }

  if (vt_out) {
    // epilogue: LDS transpose.  Cs[col][130] (pad -> conflict-free), then
    // coalesced bf16x8 stores along m into Vt[bh][d][m].
    bf16_t* Cs = smem;
    __syncthreads();  // all waves done reading As/Bs
#pragma unroll
    for (int nt = 0; nt < 4; ++nt) {
      int col = n0w + nt * 16 + l15;
      float bc = bias[nbase + col];
#pragma unroll
      for (int mt = 0; mt < MT; ++mt) {
        int ml = m0w + mt * 16 + quad * 4;
        bf16x4 vv;
#pragma unroll
        for (int r = 0; r < 4; ++r) vv[r] = (bf16_t)(acc[mt][nt][r] + bc);
        *(bf16x4*)&Cs[col * 130 + ml] = vv;
      }
    }
    __syncthreads();
    int bb = mbase >> 10, ml0 = mbase & 1023;
#pragma unroll
    for (int f = 0; f < 8; ++f) {
      int chunk = t + f * 256;
      int col = chunk >> 4, m8 = (chunk & 15) * 8;
      bf16x8 val = *(const bf16x8*)&Cs[col * 130 + m8];
      int d = (nbase + col) & 63, hh = (nbase + col) >> 6;
      *(bf16x8*)&((bf16_t*)Cv)[((size_t)((bb * NH + hh) * DK + d)) * SEQ + ml0 + m8] = val;
    }
  } else {
#pragma unroll
    for (int nt = 0; nt < 4; ++nt) {
      int col = nbase + n0w + nt * 16 + l15;
      float bc = bias[col];
#pragma unroll
      for (int mt = 0; mt < MT; ++mt)
#pragma unroll
        for (int r = 0; r < 4; ++r) {
          int row = mbase + m0w + mt * 16 + quad * 4 + r;
          float vv = acc[mt][nt][r] + bc;
          if (OUTF32)
            ((float*)Cv)[(size_t)row * DM + col] = vv;
          else
            ((bf16_t*)Cv)[(size_t)row * DM + col] = (bf16_t)vv;
        }
    }
  }
}

__global__ __launch_bounds__(256) void gemm_qkv_kernel(
    const bf16_t* xq, const bf16_t* xk, const bf16_t* xv,
    const bf16_t* wq, const bf16_t* wk, const bf16_t* wv,
    const float* bq, const float* bk, const float* bv,
    bf16_t* cq, bf16_t* ck, bf16_t* vt) {
  int z = blockIdx.z;
  const bf16_t* X;
  const bf16_t* W;
  const float* bias;
  bf16_t* C;
  if (z == 0)      { X = xq; W = wq; bias = bq; C = cq; }
  else if (z == 1) { X = xk; W = wk; bias = bk; C = ck; }
  else             { X = xv; W = wv; bias = bv; C = vt; }
  gemm_core<128, false>(X, W, bias, C, blockIdx.x, blockIdx.y, z == 2);
}

__global__ __launch_bounds__(256) void gemm_wo_kernel(const bf16_t* X, const bf16_t* W,
                                                      const float* bias, float* C) {
  gemm_core<64, true>(X, W, bias, C, blockIdx.x, blockIdx.y, false);
}

// ---------------------------------------------------------------------------
// Flash attention (R7 structure + VALU diet).  64 q x (h,b) per block.
// S^T = mfma(K,Q); softmax per q=l15 in EXP2 domain (G pre-scaled f32);
// wave-private LDS P; O^T += V^T P^T.  K/V/G register-prefetched.
// ---------------------------------------------------------------------------
__global__ __launch_bounds__(256) void flash_mfma_kernel(const bf16_t* __restrict__ Qb,
                                                         const bf16_t* __restrict__ Kb,
                                                         const bf16_t* __restrict__ Vt,
                                                         const float* __restrict__ G,
                                                         bf16_t* __restrict__ Ab) {
  int qt = blockIdx.x, h = blockIdx.y, b = blockIdx.z;
  __shared__ bf16_t Qs[64][72];
  __shared__ bf16_t Ks[64][72];
  __shared__ bf16_t Vs[64][72];
  __shared__ bf16_t Ps[64][72];
  int t = threadIdx.x, lane = t & 63, w = t >> 6;
  int quad = lane >> 4, l15 = lane & 15;

#pragma unroll
  for (int f = 0; f < 2; ++f) {
    int chunk = t + f * 256;
    int row = chunk >> 3, k8 = (chunk & 7) * 8;
    *(bf16x8*)&Qs[row][k8] =
        *(const bf16x8*)&Qb[(size_t)(b * SEQ + qt * 64 + row) * DM + h * DK + k8];
  }
  __syncthreads();
  bf16x8 aq0 = *(const bf16x8*)&Qs[w * 16 + l15][quad * 8];
  bf16x8 aq1 = *(const bf16x8*)&Qs[w * 16 + l15][32 + quad * 8];

  float m_st = -INFINITY, l_st = 0.f;
  f32x4 o[4] = {};
  const size_t grow = (size_t)(b * SEQ + qt * 64 + w * 16 + l15) * SEQ;

  int srow[2], sk8[2];
#pragma unroll
  for (int f = 0; f < 2; ++f) {
    int chunk = t + f * 256;
    srow[f] = chunk >> 3;
    sk8[f] = (chunk & 7) * 8;
  }
  const bf16_t* Kbase = Kb + (size_t)b * SEQ * DM + h * DK;
  const bf16_t* Vbase = Vt + (size_t)(b * NH + h) * DK * SEQ;
  bf16x8 kreg[2], vreg[2];
  f32x4 greg[4];
#pragma unroll
  for (int f = 0; f < 2; ++f) {
    kreg[f] = *(const bf16x8*)&Kbase[(size_t)srow[f] * DM + sk8[f]];
    vreg[f] = *(const bf16x8*)&Vbase[(size_t)srow[f] * SEQ + sk8[f]];
  }
#pragma unroll
  for (int ct = 0; ct < 4; ++ct)
    greg[ct] = *(const f32x4*)&G[grow + ct * 16 + quad * 4];

  for (int mt = 0; mt < 16; ++mt) {
    __syncthreads();
#pragma unroll
    for (int f = 0; f < 2; ++f) {
      *(bf16x8*)&Ks[srow[f]][sk8[f]] = kreg[f];
      *(bf16x8*)&Vs[srow[f]][sk8[f]] = vreg[f];
    }
    __syncthreads();
    if (mt + 1 < 16) {
#pragma unroll
      for (int f = 0; f < 2; ++f) {
        kreg[f] = *(const bf16x8*)&Kbase[(size_t)((mt + 1) * 64 + srow[f]) * DM + sk8[f]];
        vreg[f] = *(const bf16x8*)&Vbase[(size_t)srow[f] * SEQ + (mt + 1) * 64 + sk8[f]];
      }
    }

    f32x4 s[4];
#pragma unroll
    for (int ct = 0; ct < 4; ++ct) {
      bf16x8 ak0 = *(const bf16x8*)&Ks[ct * 16 + l15][quad * 8];
      bf16x8 ak1 = *(const bf16x8*)&Ks[ct * 16 + l15][32 + quad * 8];
      f32x4 z = {};
      s[ct] = mfma32(ak1, aq1, mfma32(ak0, aq0, z));
    }

    float sv[4][4];
    float rm = -INFINITY;
#pragma unroll
    for (int ct = 0; ct < 4; ++ct) {
#pragma unroll
      for (int r = 0; r < 4; ++r) {
        float x = s[ct][r] * greg[ct][r];  // G pre-scaled by 0.125*log2e
        sv[ct][r] = x;
        rm = fmaxf(rm, x);
      }
    }
    if (mt + 1 < 16) {
#pragma unroll
      for (int ct = 0; ct < 4; ++ct)
        greg[ct] = *(const f32x4*)&G[grow + (mt + 1) * 64 + ct * 16 + quad * 4];
    }
    rm = fmaxf(rm, __shfl_xor(rm, 16, 64));
    rm = fmaxf(rm, __shfl_xor(rm, 32, 64));
    float mnew = fmaxf(m_st, rm);
    float alpha = __builtin_amdgcn_exp2f(m_st - mnew);
    m_st = mnew;

    float rs = 0.f;
#pragma unroll
    for (int ct = 0; ct < 4; ++ct) {
      bf16x4 pb;
#pragma unroll
      for (int r = 0; r < 4; ++r) {
        float p = __builtin_amdgcn_exp2f(sv[ct][r] - mnew);
        pb[r] = (bf16_t)p;
        rs += p;
      }
      *(bf16x4*)&Ps[w * 16 + l15][ct * 16 + quad * 4] = pb;
    }
    rs += __shfl_xor(rs, 16, 64);
    rs += __shfl_xor(rs, 32, 64);
    l_st = l_st * alpha + rs;

#pragma unroll
    for (int dt = 0; dt < 4; ++dt) {
      o[dt][0] *= alpha; o[dt][1] *= alpha; o[dt][2] *= alpha; o[dt][3] *= alpha;
    }
#pragma unroll
    for (int c = 0; c < 2; ++c) {
      bf16x8 bp = *(const bf16x8*)&Ps[w * 16 + l15][c * 32 + quad * 8];
#pragma unroll
      for (int dt = 0; dt < 4; ++dt) {
        bf16x8 av = *(const bf16x8*)&Vs[dt * 16 + l15][c * 32 + quad * 8];
        o[dt] = mfma32(av, bp, o[dt]);
      }
    }
  }

  float linv = 1.0f / l_st;
  size_t qrow = (size_t)(b * SEQ + qt * 64 + w * 16 + l15);
#pragma unroll
  for (int dt = 0; dt < 4; ++dt)
#pragma unroll
    for (int r = 0; r < 4; ++r)
      Ab[qrow * DM + h * DK + dt * 16 + quad * 4 + r] = (bf16_t)(o[dt][r] * linv);
}

// ---------------------------------------------------------------------------
extern "C" void kernel_launch(void* const* d_in, const int* in_sizes, int n_in,
                              void* d_out, int out_size, void* d_ws, size_t ws_size,
                              hipStream_t stream) {
  const float* query = (const float*)d_in[0];
  const float* key = (const float*)d_in[1];
  const float* value = (const float*)d_in[2];
  const float* wc = (const float*)d_in[3];
  const float* Wq = (const float*)d_in[4];
  const float* bq = (const float*)d_in[5];
  const float* Wk = (const float*)d_in[6];
  const float* bk = (const float*)d_in[7];
  const float* Wv = (const float*)d_in[8];
  const float* bv = (const float*)d_in[9];
  const float* Wo = (const float*)d_in[10];
  const float* bo = (const float*)d_in[11];
  float* out = (float*)d_out;

  const size_t ACT = (size_t)ROWS * DM;
  const size_t WSZ = (size_t)DM * DM;
  bf16_t* Qb = (bf16_t*)d_ws;
  bf16_t* Kb = Qb + ACT;
  bf16_t* Vt = Kb + ACT;
  bf16_t* Ab = Vt + ACT;
  bf16_t* Xq = Ab + ACT;
  bf16_t* Xk = Xq + ACT;
  bf16_t* Xv = Xk + ACT;
  bf16_t* Wqb = Xv + ACT;
  bf16_t* Wkb = Wqb + WSZ;
  bf16_t* Wvb = Wkb + WSZ;
  bf16_t* Wob = Wvb + WSZ;
  float* G = (float*)(Wob + WSZ);  // 8*1024*1024 f32 = 33.5 MB

  prep_kernel<<<3712, 256, 0, stream>>>(query, key, value, Wq, Wk, Wv, Wo, wc,
                                        Xq, Xk, Xv, Wqb, Wkb, Wvb, Wob, G);

  gemm_qkv_kernel<<<dim3(ROWS / 128, DM / 128, 3), 256, 0, stream>>>(
      Xq, Xk, Xv, Wqb, Wkb, Wvb, bq, bk, bv, Qb, Kb, Vt);

  flash_mfma_kernel<<<dim3(SEQ / 64, NH, BS), 256, 0, stream>>>(Qb, Kb, Vt, G, Ab);

  gemm_wo_kernel<<<dim3(ROWS / 64, DM / 128), 256, 0, stream>>>(Ab, Wob, bo, out);
}